// Round 1
// 524.379 us; speedup vs baseline: 1.1948x; 1.1948x over previous
//
#include <hip/hip_runtime.h>
#include <math.h>

// Shapes
#define B_   128
#define D_   1024
#define H_   256
#define M_   100
#define K_   5
#define MD   102400   // M_*D_
#define EPS_ 1e-5f

// d_out layout (f32): probs[128*100*1024], scores[12800], syn[12800], logits[128*100*1024]
#define OFF_SCORES 13107200
#define OFF_SYN    13120000
#define OFF_LOGITS 13132800

// ---------------- reduction helpers ----------------
__device__ __forceinline__ float block_sum(float v, float* red, int t) {
  #pragma unroll
  for (int off = 1; off < 64; off <<= 1) v += __shfl_xor(v, off);
  if ((t & 63) == 0) red[t >> 6] = v;
  __syncthreads();
  float s = red[0] + red[1] + red[2] + red[3];
  __syncthreads();
  return s;
}

__device__ __forceinline__ float block_max(float v, float* red, int t) {
  #pragma unroll
  for (int off = 1; off < 64; off <<= 1) v = fmaxf(v, __shfl_xor(v, off));
  if ((t & 63) == 0) red[t >> 6] = v;
  __syncthreads();
  float s = fmaxf(fmaxf(red[0], red[1]), fmaxf(red[2], red[3]));
  __syncthreads();
  return s;
}

__device__ __forceinline__ void block_sum2(float& a, float& b, float* red, int t) {
  #pragma unroll
  for (int off = 1; off < 64; off <<= 1) { a += __shfl_xor(a, off); b += __shfl_xor(b, off); }
  if ((t & 63) == 0) { red[(t >> 6) * 2] = a; red[(t >> 6) * 2 + 1] = b; }
  __syncthreads();
  a = red[0] + red[2] + red[4] + red[6];
  b = red[1] + red[3] + red[5] + red[7];
  __syncthreads();
}

// ---------------- K1: generator layers 1+2 (per batch row) ----------------
__global__ __launch_bounds__(256) void gen_mlp_kernel(
    const float* __restrict__ x,
    const float* __restrict__ gW1, const float* __restrict__ gb1,
    const float* __restrict__ ln1s, const float* __restrict__ ln1b,
    const float* __restrict__ gW2, const float* __restrict__ gb2,
    const float* __restrict__ ln2s, const float* __restrict__ ln2b,
    float* __restrict__ h2out)
{
  __shared__ float xs[1024];
  __shared__ float h1s[512];
  __shared__ float red[8];
  int b = blockIdx.x, t = threadIdx.x;
  const float* xr = x + b * 1024;
  #pragma unroll
  for (int i = 0; i < 4; ++i) xs[t + i * 256] = xr[t + i * 256];
  __syncthreads();

  // layer1: thread computes outputs o=2t, 2t+1 (512 outputs)
  float a0 = 0.f, a1 = 0.f;
  for (int d = 0; d < 1024; ++d) {
    float xv = xs[d];
    float2 w = *(const float2*)&gW1[d * 512 + 2 * t];
    a0 = fmaf(xv, w.x, a0);
    a1 = fmaf(xv, w.y, a1);
  }
  a0 += gb1[2 * t]; a1 += gb1[2 * t + 1];
  float s = a0 + a1, sq = a0 * a0 + a1 * a1;
  block_sum2(s, sq, red, t);
  float mu = s * (1.f / 512.f);
  float var = sq * (1.f / 512.f) - mu * mu;
  float inv = rsqrtf(var + EPS_);
  h1s[2 * t]     = fmaxf((a0 - mu) * inv * ln1s[2 * t]     + ln1b[2 * t],     0.f);
  h1s[2 * t + 1] = fmaxf((a1 - mu) * inv * ln1s[2 * t + 1] + ln1b[2 * t + 1], 0.f);
  __syncthreads();

  // layer2: thread computes output o=t (256 outputs)
  float acc = 0.f;
  for (int h = 0; h < 512; ++h) acc = fmaf(h1s[h], gW2[h * 256 + t], acc);
  acc += gb2[t];
  float s2 = acc, sq2 = acc * acc;
  block_sum2(s2, sq2, red, t);
  float mu2 = s2 * (1.f / 256.f);
  float var2 = sq2 * (1.f / 256.f) - mu2 * mu2;
  float inv2 = rsqrtf(var2 + EPS_);
  h2out[b * 256 + t] = fmaxf((acc - mu2) * inv2 * ln2s[t] + ln2b[t], 0.f);
}

// ---------------- K2: logits = h2 @ gW3 + gb3  (128 x 102400, K=256) ----------------
// Register-tiled fp32 GEMM: block = 64 cols x all 128 rows; thread = 8 rows x 4 cols.
// Latency fix vs prior version: explicit 8-deep rolling register prefetch of gW3
// (8 outstanding 16B loads/wave covers ~900cy HBM latency), pre-loads issued
// before staging, float4 staging reads, 2-way (free) LDS write banking.
__global__ __launch_bounds__(256, 4) void gemm3_kernel(
    const float* __restrict__ h2, const float* __restrict__ gW3,
    const float* __restrict__ gb3, float* __restrict__ logits)
{
  __shared__ float h2t[64 * 132];  // [kk][b], stride 132: 16B-aligned rows, conflict-free b128 reads
  int t = threadIdx.x;
  int col0 = blockIdx.x * 64;
  int c4 = (t & 15) * 4;
  int r8 = (t >> 4) * 8;
  float acc[8][4];
  #pragma unroll
  for (int i = 0; i < 8; ++i)
    #pragma unroll
    for (int j = 0; j < 4; ++j) acc[i][j] = 0.f;

  int bb = t >> 1;              // staging: row 0..127
  int k0 = (t & 1) * 32;        // staging: k offset 0 or 32

  #pragma unroll 1
  for (int c = 0; c < 4; ++c) {
    // issue the first 8 gW3 prefetches BEFORE staging so they overlap it
    const float* wp = &gW3[(c * 64) * MD + col0 + c4];
    float4 pre[8];
    #pragma unroll
    for (int u = 0; u < 8; ++u) pre[u] = *(const float4*)(wp + u * MD);

    // stage h2[:, c*64 .. c*64+63] transposed into LDS (float4 reads, 2-way-free writes)
    {
      const float* hp = &h2[bb * 256 + c * 64 + k0];
      #pragma unroll
      for (int j = 0; j < 8; ++j) {
        float4 hv = *(const float4*)(hp + j * 4);
        int k = k0 + j * 4;
        h2t[(k + 0) * 132 + bb] = hv.x;
        h2t[(k + 1) * 132 + bb] = hv.y;
        h2t[(k + 2) * 132 + bb] = hv.z;
        h2t[(k + 3) * 132 + bb] = hv.w;
      }
    }
    __syncthreads();

    // main loop: 8 groups of 8 kk; rolling 8-deep prefetch
    const float* wl = wp + 8 * MD;
    #pragma unroll 1
    for (int kg = 0; kg < 7; ++kg) {
      int kb = kg * 8;
      #pragma unroll
      for (int u = 0; u < 8; ++u) {
        float4 bf = pre[u];
        pre[u] = *(const float4*)(wl + u * MD);
        float4 af0 = *(const float4*)&h2t[(kb + u) * 132 + r8];
        float4 af1 = *(const float4*)&h2t[(kb + u) * 132 + r8 + 4];
        float a[8] = {af0.x, af0.y, af0.z, af0.w, af1.x, af1.y, af1.z, af1.w};
        float bv[4] = {bf.x, bf.y, bf.z, bf.w};
        #pragma unroll
        for (int i = 0; i < 8; ++i)
          #pragma unroll
          for (int j = 0; j < 4; ++j) acc[i][j] = fmaf(a[i], bv[j], acc[i][j]);
      }
      wl += 8 * MD;
    }
    // tail group kk = 56..63 (no further prefetch)
    #pragma unroll
    for (int u = 0; u < 8; ++u) {
      float4 bf = pre[u];
      float4 af0 = *(const float4*)&h2t[(56 + u) * 132 + r8];
      float4 af1 = *(const float4*)&h2t[(56 + u) * 132 + r8 + 4];
      float a[8] = {af0.x, af0.y, af0.z, af0.w, af1.x, af1.y, af1.z, af1.w};
      float bv[4] = {bf.x, bf.y, bf.z, bf.w};
      #pragma unroll
      for (int i = 0; i < 8; ++i)
        #pragma unroll
        for (int j = 0; j < 4; ++j) acc[i][j] = fmaf(a[i], bv[j], acc[i][j]);
    }
    __syncthreads();
  }

  float4 bias = *(const float4*)&gb3[col0 + c4];
  #pragma unroll
  for (int i = 0; i < 8; ++i) {
    float4 o;
    o.x = acc[i][0] + bias.x; o.y = acc[i][1] + bias.y;
    o.z = acc[i][2] + bias.z; o.w = acc[i][3] + bias.w;
    *(float4*)&logits[(r8 + i) * MD + col0 + c4] = o;
  }
}

// ---------------- K3: softmax + top-5 + gathers + synergy + t1 (per (b,m) row) ----------------
__global__ __launch_bounds__(256) void tail_kernel(
    const float* __restrict__ x, const float* __restrict__ gumbel,
    const float* __restrict__ sW1, const float* __restrict__ sb1,
    const float* __restrict__ yW1, const float* __restrict__ yb1,
    const float* __restrict__ yW2, const float* __restrict__ yb2,
    const float* __restrict__ logits, float* __restrict__ probs,
    float* __restrict__ syn, float* __restrict__ t1ws)
{
  __shared__ float red[8];
  __shared__ float redv[4];
  __shared__ int   redi[4];
  __shared__ int   winner;
  int row = blockIdx.x;       // row = b*100 + m
  int t = threadIdx.x;
  int b = row / 100;
  const float* lg = logits + row * 1024;
  const float* gm = gumbel + row * 1024;

  // z = (logit + gumbel) / tau, tau = 0.5
  float z[4];
  #pragma unroll
  for (int i = 0; i < 4; ++i) z[i] = (lg[t + i * 256] + gm[t + i * 256]) * 2.0f;
  float mx = fmaxf(fmaxf(z[0], z[1]), fmaxf(z[2], z[3]));
  mx = block_max(mx, red, t);
  float p[4]; float ls = 0.f;
  #pragma unroll
  for (int i = 0; i < 4; ++i) { p[i] = expf(z[i] - mx); ls += p[i]; }
  float denom = block_sum(ls, red, t);
  float inv = 1.f / denom;
  float v[4];
  #pragma unroll
  for (int i = 0; i < 4; ++i) {
    v[i] = p[i] * inv;
    probs[row * 1024 + t + i * 256] = v[i];
  }

  // top-5 on written prob values; tie-break: lower index first (jax.lax.top_k stable order)
  float t1acc = sb1[t];
  float u1acc = yb1[t];
  for (int jsel = 0; jsel < 5; ++jsel) {
    float bv = v[0]; int bi = t;          // idx = i*256 + t
    #pragma unroll
    for (int i = 1; i < 4; ++i) {
      int idx = i * 256 + t;
      if (v[i] > bv || (v[i] == bv && idx < bi)) { bv = v[i]; bi = idx; }
    }
    #pragma unroll
    for (int off = 1; off < 64; off <<= 1) {
      float ov = __shfl_xor(bv, off);
      int oi = __shfl_xor(bi, off);
      if (ov > bv || (ov == bv && oi < bi)) { bv = ov; bi = oi; }
    }
    if ((t & 63) == 0) { redv[t >> 6] = bv; redi[t >> 6] = bi; }
    __syncthreads();
    if (t == 0) {
      float wv = redv[0]; int wi = redi[0];
      #pragma unroll
      for (int w = 1; w < 4; ++w)
        if (redv[w] > wv || (redv[w] == wv && redi[w] < wi)) { wv = redv[w]; wi = redi[w]; }
      winner = wi;
    }
    __syncthreads();
    int w = winner;
    if ((w & 255) == t) v[w >> 8] = -1.f;   // mask selected
    float xv = x[b * 1024 + w];             // uniform (scalar) load
    t1acc = fmaf(xv, sW1[(jsel * 1024 + w) * 256 + t], t1acc);
    u1acc = fmaf(xv, yW1[(jsel * 1024 + w) * 256 + t], u1acc);
    __syncthreads();
  }

  float t1v = fmaxf(t1acc, 0.f);
  float u1v = fmaxf(u1acc, 0.f);
  t1ws[row * 256 + t] = t1v;

  // synergy = tanh(u1 . yW2 + yb2)
  float part = u1v * yW2[t];
  float dsum = block_sum(part, red, t);
  if (t == 0) syn[row] = tanhf(dsum + yb2[0]);
}

// ---------------- K4: scores = sigmoid(relu(t1 @ sW2 + sb2) @ sW3 + sb3) ----------------
// Block = 64 rows x 128 cols, K=256; thread = 8 rows x 4 cols.
__global__ __launch_bounds__(256) void scorer2_kernel(
    const float* __restrict__ t1, const float* __restrict__ sW2,
    const float* __restrict__ sb2, const float* __restrict__ sW3,
    const float* __restrict__ sb3, float* __restrict__ scores)
{
  __shared__ float t1t[64 * 68];   // [kk][row], stride 68 (16B-aligned)
  __shared__ float red[64 * 32];
  int t = threadIdx.x;
  int row0 = blockIdx.x * 64;
  int c4 = (t & 31) * 4;
  int r8 = (t >> 5) * 8;
  float acc[8][4];
  #pragma unroll
  for (int i = 0; i < 8; ++i)
    #pragma unroll
    for (int j = 0; j < 4; ++j) acc[i][j] = 0.f;

  for (int c = 0; c < 4; ++c) {
    #pragma unroll
    for (int p = 0; p < 16; ++p) {
      int rr = p * 4 + (t >> 6);
      int kk = t & 63;
      t1t[kk * 68 + rr] = t1[(row0 + rr) * 256 + c * 64 + kk];
    }
    __syncthreads();
    #pragma unroll 4
    for (int kk = 0; kk < 64; ++kk) {
      float4 bf = *(const float4*)&sW2[(c * 64 + kk) * 128 + c4];
      float4 a0 = *(const float4*)&t1t[kk * 68 + r8];
      float4 a1 = *(const float4*)&t1t[kk * 68 + r8 + 4];
      float a[8] = {a0.x, a0.y, a0.z, a0.w, a1.x, a1.y, a1.z, a1.w};
      float bv[4] = {bf.x, bf.y, bf.z, bf.w};
      #pragma unroll
      for (int i = 0; i < 8; ++i)
        #pragma unroll
        for (int j = 0; j < 4; ++j) acc[i][j] = fmaf(a[i], bv[j], acc[i][j]);
    }
    __syncthreads();
  }

  float4 b2 = *(const float4*)&sb2[c4];
  float4 w3 = *(const float4*)&sW3[c4];
  #pragma unroll
  for (int i = 0; i < 8; ++i) {
    float s = fmaxf(acc[i][0] + b2.x, 0.f) * w3.x
            + fmaxf(acc[i][1] + b2.y, 0.f) * w3.y
            + fmaxf(acc[i][2] + b2.z, 0.f) * w3.z
            + fmaxf(acc[i][3] + b2.w, 0.f) * w3.w;
    red[(r8 + i) * 32 + (t & 31)] = s;
  }
  __syncthreads();
  if (t < 64) {
    float s = sb3[0];
    #pragma unroll
    for (int g = 0; g < 32; ++g) s += red[t * 32 + g];
    scores[row0 + t] = 1.f / (1.f + expf(-s));
  }
}

extern "C" void kernel_launch(void* const* d_in, const int* in_sizes, int n_in,
                              void* d_out, int out_size, void* d_ws, size_t ws_size,
                              hipStream_t stream) {
  const float* x    = (const float*)d_in[0];
  const float* gum  = (const float*)d_in[1];
  const float* gW1  = (const float*)d_in[2];
  const float* gb1  = (const float*)d_in[3];
  const float* ln1s = (const float*)d_in[4];
  const float* ln1b = (const float*)d_in[5];
  const float* gW2  = (const float*)d_in[6];
  const float* gb2  = (const float*)d_in[7];
  const float* ln2s = (const float*)d_in[8];
  const float* ln2b = (const float*)d_in[9];
  const float* gW3  = (const float*)d_in[10];
  const float* gb3  = (const float*)d_in[11];
  const float* sW1  = (const float*)d_in[12];
  const float* sb1  = (const float*)d_in[13];
  const float* sW2  = (const float*)d_in[14];
  const float* sb2  = (const float*)d_in[15];
  const float* sW3  = (const float*)d_in[16];
  const float* sb3  = (const float*)d_in[17];
  const float* yW1  = (const float*)d_in[18];
  const float* yb1  = (const float*)d_in[19];
  const float* yW2  = (const float*)d_in[20];
  const float* yb2  = (const float*)d_in[21];

  float* out    = (float*)d_out;
  float* probs  = out;
  float* scores = out + OFF_SCORES;
  float* syn    = out + OFF_SYN;
  float* logits = out + OFF_LOGITS;

  float* h2 = (float*)d_ws;                              // 128*256 f32 (131072 floats)
  float* t1 = (float*)((char*)d_ws + 131072 * 4);        // 12800*256 f32 = 13.1 MB

  gen_mlp_kernel<<<128, 256, 0, stream>>>(x, gW1, gb1, ln1s, ln1b, gW2, gb2, ln2s, ln2b, h2);
  gemm3_kernel<<<1600, 256, 0, stream>>>(h2, gW3, gb3, logits);
  tail_kernel<<<12800, 256, 0, stream>>>(x, gum, sW1, sb1, yW1, yb1, yW2, yb2,
                                         logits, probs, syn, t1);
  scorer2_kernel<<<200, 256, 0, stream>>>(t1, sW2, sb2, sW3, sb3, scores);
}